// Round 6
// baseline (491.700 us; speedup 1.0000x reference)
//
#include <hip/hip_runtime.h>
#include <hip/hip_bf16.h>

typedef unsigned short u16;
typedef __bf16 bf16x8 __attribute__((ext_vector_type(8)));
typedef float  f32x4  __attribute__((ext_vector_type(4)));

constexpr int TT = 4096;   // seq
constexpr int BBATCH = 2;  // batch
constexpr int EE = 1024;   // embed
constexpr int HH = 16;     // heads
constexpr int DD = 64;     // head dim
constexpr int WQ = 256;    // one-sided window
constexpr int GG = 64;     // global tokens
constexpr int NSPLIT = 8;  // key splits for global attention

// ---------- bf16 helpers ----------
__device__ __forceinline__ u16 f2bf(float f) {
    union { float f; unsigned int i; } c; c.f = f;
    unsigned int x = c.i;
    return (u16)((x + 0x7fffu + ((x >> 16) & 1u)) >> 16);  // RNE
}
__device__ __forceinline__ uint4 pack8(float4 a, float4 b) {
    uint4 r;
    r.x = (unsigned)f2bf(a.x) | ((unsigned)f2bf(a.y) << 16);
    r.y = (unsigned)f2bf(a.z) | ((unsigned)f2bf(a.w) << 16);
    r.z = (unsigned)f2bf(b.x) | ((unsigned)f2bf(b.y) << 16);
    r.w = (unsigned)f2bf(b.z) | ((unsigned)f2bf(b.w) << 16);
    return r;
}

// async global->LDS, 16B per lane; LDS dest = wave-uniform base + lane*16
__device__ __forceinline__ void g2l16(const u16* g, u16* l) {
    __builtin_amdgcn_global_load_lds(
        (const __attribute__((address_space(1))) void*)g,
        (__attribute__((address_space(3))) void*)l, 16, 0, 0);
}

// ---------- fp32 -> bf16 conversion: 7 weights + query (perm [T,B,E]->[B,T,E]) ----------
struct WPtrs { const float* p[7]; };
__global__ __launch_bounds__(256) void conv_kernel(
    WPtrs wp, const float* __restrict__ query, u16* __restrict__ wb, u16* __restrict__ xb)
{
    const size_t i8 = ((size_t)blockIdx.x * 256 + threadIdx.x) << 3;
    const size_t WTOT = (size_t)7 << 20;   // 7 x 1024*1024
    const float* src;
    u16* dst;
    if (i8 < WTOT) {
        const int which = (int)(i8 >> 20);
        src = wp.p[which] + (i8 & (((size_t)1 << 20) - 1));
        dst = wb + i8;
    } else {
        const size_t j = i8 - WTOT;            // dst index in [B,T,E]
        const size_t e = j & (EE - 1);
        const size_t t = (j >> 10) & (TT - 1);
        const size_t b = j >> 22;
        src = query + (t * BBATCH + b) * EE + e;
        dst = xb + j;
    }
    const float4 f0 = *(const float4*)src;
    const float4 f1 = *(const float4*)(src + 4);
    *(uint4*)dst = pack8(f0, f1);
}

// ---------- GEMM (m97 structure): C = (A @ W^T + bias) * scale, A/W bf16, K=N=1024 ----------
// PERMA_QG: logical row m reads source row (m>>6)*4096 + (m&63)  (x[:, :G] gather, M=128)
// PERMC: 0 = none; 1 = store row m=b*T+t to row t*2+b fp32 ([B,T]->[T,B]); 2 = store V
//        transposed per head: vt[((b*H+h)*64+d)*T + t] (packed ushort4 along t).
template<int C_F32, int PERMA_QG, int PERMC>
__global__ __launch_bounds__(256) void gemm_kernel(
    const u16* __restrict__ A, const u16* __restrict__ W, const float* __restrict__ bias,
    void* __restrict__ Cv, float scale)
{
    const int tid = threadIdx.x, lane = tid & 63, w = tid >> 6;
    const int wm = w >> 1, wn = w & 1;
    const int m0 = blockIdx.y << 7, n0 = blockIdx.x << 7;

    __shared__ __align__(16) u16 As[128 * 32];
    __shared__ __align__(16) u16 Bs[128 * 32];

    const int lrow = lane >> 2;            // 4 lanes per 64B row
    const int lcol = (lane & 3) << 3;
    auto arow = [](int m) -> size_t {
        return PERMA_QG ? (size_t)(((m >> 6) << 12) | (m & 63)) : (size_t)m;
    };
    const u16* gA0 = A + arow(m0 + (w << 4) + lrow) * EE + lcol;
    const u16* gA1 = A + arow(m0 + 64 + (w << 4) + lrow) * EE + lcol;
    const u16* gB0 = W + (size_t)(n0 + (w << 4) + lrow) * EE + lcol;
    const u16* gB1 = gB0 + (size_t)64 * EE;
    u16* lA0 = As + (w << 9);              // wave-uniform LDS bases (1024B apart)
    u16* lA1 = As + 2048 + (w << 9);
    u16* lB0 = Bs + (w << 9);
    u16* lB1 = Bs + 2048 + (w << 9);

    f32x4 acc[4][4];
#pragma unroll
    for (int i = 0; i < 4; i++)
#pragma unroll
        for (int j = 0; j < 4; j++)
            acc[i][j] = (f32x4){0.f, 0.f, 0.f, 0.f};

    const int fr = lane & 15;
    const int fq = (lane >> 4) << 3;

    for (int k0 = 0; k0 < EE; k0 += 32) {
        g2l16(gA0 + k0, lA0);
        g2l16(gA1 + k0, lA1);
        g2l16(gB0 + k0, lB0);
        g2l16(gB1 + k0, lB1);
        __syncthreads();
        bf16x8 af[4], bfv[4];
#pragma unroll
        for (int i = 0; i < 4; i++)
            af[i] = *(const bf16x8*)&As[((wm << 6) + (i << 4) + fr) * 32 + fq];
#pragma unroll
        for (int j = 0; j < 4; j++)
            bfv[j] = *(const bf16x8*)&Bs[((wn << 6) + (j << 4) + fr) * 32 + fq];
#pragma unroll
        for (int i = 0; i < 4; i++)
#pragma unroll
            for (int j = 0; j < 4; j++)
                acc[i][j] = __builtin_amdgcn_mfma_f32_16x16x32_bf16(af[i], bfv[j], acc[i][j], 0, 0, 0);
        __syncthreads();
    }

    const int colbase = n0 + (wn << 6);
    const int rowbase = m0 + (wm << 6) + ((lane >> 4) << 2);
#pragma unroll
    for (int j = 0; j < 4; j++) {
        const int col = colbase + (j << 4) + fr;
        const float bv = bias[col];
#pragma unroll
        for (int i = 0; i < 4; i++) {
            if (PERMC == 2) {
                // vt[((b*H+h)*64+d)*T + t], 4 consecutive t packed
                const int row0 = rowbase + (i << 4);       // t multiple of 4
                const int bb = row0 >> 12, t = row0 & (TT - 1);
                const int hh = col >> 6, d = col & 63;
                ushort4 pk;
                pk.x = f2bf((acc[i][j][0] + bv) * scale);
                pk.y = f2bf((acc[i][j][1] + bv) * scale);
                pk.z = f2bf((acc[i][j][2] + bv) * scale);
                pk.w = f2bf((acc[i][j][3] + bv) * scale);
                *(ushort4*)((u16*)Cv + (((size_t)(bb * HH + hh) * DD + d) * TT + t)) = pk;
            } else {
#pragma unroll
                for (int r = 0; r < 4; r++) {
                    const int row = rowbase + (i << 4) + r;
                    const float val = (acc[i][j][r] + bv) * scale;
                    const size_t dst = (size_t)(PERMC == 1 ? (((row & (TT - 1)) << 1) | (row >> 12)) : row) * EE + col;
                    if (C_F32) ((float*)Cv)[dst] = val;
                    else       ((u16*)Cv)[dst]   = f2bf(val);
                }
            }
        }
    }
}

// ---------- band attention, barrier-free MFMA flash ----------
// blockIdx.x = qt*32 + (b*H+h) (XCD slab locality). Q/K frags loaded DIRECTLY from
// global (16B contiguous per lane); V frags directly from pre-transposed vt[b,h,d,t].
// Only per-wave LDS (P round-trip) -> zero __syncthreads, waves fully independent.
// Out-of-range chunks skipped (64-aligned => all-in or all-out; exp(-1e9)==0 exactly).
__global__ __launch_bounds__(256) void band_attn_kernel(
    const u16* __restrict__ q, const u16* __restrict__ k, const u16* __restrict__ vt,
    u16* __restrict__ attnb)
{
    const int tid  = threadIdx.x;
    const int lane = tid & 63;
    const int w    = tid >> 6;
    const int col  = lane & 15;
    const int quad = lane >> 4;

    const int qt = blockIdx.x >> 5;
    const int bh = blockIdx.x & 31;
    const int h  = bh & (HH - 1);
    const int b  = bh >> 4;
    const int t0 = qt << 6;

    __shared__ __align__(16) u16 Ps[4][16][72];   // per-wave P round-trip only

    const size_t base   = (size_t)b * TT * EE + (size_t)h * DD;
    const size_t vtbase = (size_t)bh * DD * TT;

    // Q fragments: direct global load, held for whole kernel
    const u16* qp = q + base + (size_t)(t0 + (w << 4) + col) * EE + (quad << 3);
    const bf16x8 qf0 = *(const bf16x8*)qp;
    const bf16x8 qf1 = *(const bf16x8*)(qp + 32);

    float m_i[4], l_i[4];
    f32x4 acc_o[4];
#pragma unroll
    for (int r = 0; r < 4; r++) { m_i[r] = -1e30f; l_i[r] = 0.f; }
#pragma unroll
    for (int nt = 0; nt < 4; nt++) acc_o[nt] = (f32x4){0.f, 0.f, 0.f, 0.f};

    const int c_lo = 1 + ((t0 < WQ) ? ((WQ - t0) >> 6) : 0);
    const int c_hi = min(9, 1 + ((TT + WQ - 64 - t0) >> 6));

    auto process = [&](int kpos0, int jbase) {   // jbase >= 0 -> window mask with band idx base
        // ---- QK^T (K frags direct from global) ----
        f32x4 acc_s[4];
#pragma unroll
        for (int nt = 0; nt < 4; nt++) {
            const u16* kp = k + base + (size_t)(kpos0 + (nt << 4) + col) * EE + (quad << 3);
            const bf16x8 kf0 = *(const bf16x8*)kp;
            const bf16x8 kf1 = *(const bf16x8*)(kp + 32);
            f32x4 s = (f32x4){0.f, 0.f, 0.f, 0.f};
            s = __builtin_amdgcn_mfma_f32_16x16x32_bf16(qf0, kf0, s, 0, 0, 0);
            s = __builtin_amdgcn_mfma_f32_16x16x32_bf16(qf1, kf1, s, 0, 0, 0);
            acc_s[nt] = s;
        }

        if (jbase >= 0) {
#pragma unroll
            for (int nt = 0; nt < 4; nt++) {
#pragma unroll
                for (int r = 0; r < 4; r++) {
                    const int jp   = jbase + (nt << 4) + col;
                    const int qrow = (w << 4) + (quad << 2) + r;
                    const bool ok  = (jp >= qrow) && (jp <= qrow + 2 * WQ);
                    if (!ok) acc_s[nt][r] = -1e30f;
                }
            }
        }

        // ---- online softmax ----
        float p_sum[4];
#pragma unroll
        for (int r = 0; r < 4; r++) {
            float mx = fmaxf(fmaxf(acc_s[0][r], acc_s[1][r]), fmaxf(acc_s[2][r], acc_s[3][r]));
#pragma unroll
            for (int off = 1; off < 16; off <<= 1) mx = fmaxf(mx, __shfl_xor(mx, off));
            const float m_new = fmaxf(m_i[r], mx);
            const float alpha = __expf(m_i[r] - m_new);
            m_i[r] = m_new;
            l_i[r] *= alpha;
#pragma unroll
            for (int nt = 0; nt < 4; nt++) acc_o[nt][r] *= alpha;
            float ps = 0.f;
#pragma unroll
            for (int nt = 0; nt < 4; nt++) {
                const float e = __expf(acc_s[nt][r] - m_new);
                acc_s[nt][r] = e;
                ps += e;
            }
            p_sum[r] = ps;
        }
#pragma unroll
        for (int r = 0; r < 4; r++) {
            float ps = p_sum[r];
#pragma unroll
            for (int off = 1; off < 16; off <<= 1) ps += __shfl_xor(ps, off);
            l_i[r] += ps;
        }

        // ---- P: C-layout -> per-wave LDS -> A-layout (wave-coherent, no barrier) ----
#pragma unroll
        for (int nt = 0; nt < 4; nt++)
#pragma unroll
            for (int r = 0; r < 4; r++)
                Ps[w][(quad << 2) + r][(nt << 4) + col] = f2bf(acc_s[nt][r]);

        const bf16x8 pf0 = *(const bf16x8*)&Ps[w][col][quad << 3];
        const bf16x8 pf1 = *(const bf16x8*)&Ps[w][col][32 + (quad << 3)];

        // ---- PV (V^T frags direct from vt) ----
#pragma unroll
        for (int nt = 0; nt < 4; nt++) {
            const u16* vp = vt + vtbase + (size_t)((nt << 4) + col) * TT + kpos0 + (quad << 3);
            const bf16x8 vf0 = *(const bf16x8*)vp;
            const bf16x8 vf1 = *(const bf16x8*)(vp + 32);
            acc_o[nt] = __builtin_amdgcn_mfma_f32_16x16x32_bf16(pf0, vf0, acc_o[nt], 0, 0, 0);
            acc_o[nt] = __builtin_amdgcn_mfma_f32_16x16x32_bf16(pf1, vf1, acc_o[nt], 0, 0, 0);
        }
    };

    process(0, -1);                                   // global keys [0,64), unmasked
#pragma unroll 1
    for (int c = c_lo; c <= c_hi; c++) {
        const int kpos0 = t0 - WQ + ((c - 1) << 6);
        const bool edge = (c == 1) || (c == 9);       // only partial-window chunks need mask
        process(kpos0, edge ? ((c - 1) << 6) : -1);
    }

    float inv[4];
#pragma unroll
    for (int r = 0; r < 4; r++) inv[r] = 1.f / l_i[r];
#pragma unroll
    for (int nt = 0; nt < 4; nt++) {
#pragma unroll
        for (int r = 0; r < 4; r++) {
            const int t = t0 + (w << 4) + (quad << 2) + r;
            attnb[base + (size_t)t * EE + (nt << 4) + col] = f2bf(acc_o[nt][r] * inv[r]);
        }
    }
}

// ---------- global-token attention, MFMA flash + split-K ---------- (unchanged, passing)
__global__ __launch_bounds__(256) void global_attn_flash_kernel(
    const u16* __restrict__ qg, const u16* __restrict__ kg, const u16* __restrict__ vg,
    float* __restrict__ Op, float* __restrict__ Ml, float* __restrict__ Ll)
{
    const int tid  = threadIdx.x;
    const int lane = tid & 63;
    const int w    = tid >> 6;
    const int col  = lane & 15;
    const int quad = lane >> 4;

    const int s  = blockIdx.x & (NSPLIT - 1);
    const int h  = (blockIdx.x >> 3) & (HH - 1);
    const int b  = blockIdx.x >> 7;
    const int k0pos = s * (TT / NSPLIT);

    __shared__ __align__(16) u16 Qs[64][72];
    __shared__ __align__(16) u16 Ks[64][72];
    __shared__ __align__(16) u16 Vs[64][70];
    __shared__ __align__(16) u16 Ps[4][16][72];

    const size_t base = (size_t)b * TT * EE + (size_t)h * DD;

    {
        const int qr   = tid >> 2;
        const int part = (tid & 3) << 4;
        const uint4* src = (const uint4*)(qg + (size_t)(b * GG + qr) * EE + (size_t)h * DD + part);
        *(uint4*)&Qs[qr][part]     = src[0];
        *(uint4*)&Qs[qr][part + 8] = src[1];
    }

    float m_i[4], l_i[4];
    f32x4 acc_o[4];
#pragma unroll
    for (int r = 0; r < 4; r++) { m_i[r] = -1e30f; l_i[r] = 0.f; }
#pragma unroll
    for (int nt = 0; nt < 4; nt++) acc_o[nt] = (f32x4){0.f, 0.f, 0.f, 0.f};

#pragma unroll 1
    for (int cc = 0; cc < TT / NSPLIT / 64; cc++) {
        {
            const int kk   = tid >> 2;
            const int part = (tid & 3) << 4;
            const int pos  = k0pos + (cc << 6) + kk;
            const uint4* ks = (const uint4*)(kg + base + (size_t)pos * EE + part);
            const uint4* vs = (const uint4*)(vg + base + (size_t)pos * EE + part);
            const uint4 k0v = ks[0], k1v = ks[1];
            const uint4 v0v = vs[0], v1v = vs[1];
            *(uint4*)&Ks[kk][part]     = k0v;
            *(uint4*)&Ks[kk][part + 8] = k1v;
            unsigned int* vd = (unsigned int*)&Vs[kk][part];
            vd[0] = v0v.x; vd[1] = v0v.y; vd[2] = v0v.z; vd[3] = v0v.w;
            vd[4] = v1v.x; vd[5] = v1v.y; vd[6] = v1v.z; vd[7] = v1v.w;
        }
        __syncthreads();

        bf16x8 qf0 = *(const bf16x8*)&Qs[(w << 4) + col][quad << 3];
        bf16x8 qf1 = *(const bf16x8*)&Qs[(w << 4) + col][32 + (quad << 3)];
        f32x4 acc_s[4];
#pragma unroll
        for (int nt = 0; nt < 4; nt++) {
            bf16x8 kf0 = *(const bf16x8*)&Ks[(nt << 4) + col][quad << 3];
            bf16x8 kf1 = *(const bf16x8*)&Ks[(nt << 4) + col][32 + (quad << 3)];
            f32x4 sv = (f32x4){0.f, 0.f, 0.f, 0.f};
            sv = __builtin_amdgcn_mfma_f32_16x16x32_bf16(qf0, kf0, sv, 0, 0, 0);
            sv = __builtin_amdgcn_mfma_f32_16x16x32_bf16(qf1, kf1, sv, 0, 0, 0);
            acc_s[nt] = sv;
        }

        float m_c[4], p_sum[4];
#pragma unroll
        for (int r = 0; r < 4; r++) {
            float mx = fmaxf(fmaxf(acc_s[0][r], acc_s[1][r]), fmaxf(acc_s[2][r], acc_s[3][r]));
#pragma unroll
            for (int off = 1; off < 16; off <<= 1) mx = fmaxf(mx, __shfl_xor(mx, off));
            m_c[r] = mx;
        }
#pragma unroll
        for (int r = 0; r < 4; r++) {
            const float m_new = fmaxf(m_i[r], m_c[r]);
            const float alpha = __expf(m_i[r] - m_new);
            m_i[r] = m_new;
            l_i[r] *= alpha;
#pragma unroll
            for (int nt = 0; nt < 4; nt++) acc_o[nt][r] *= alpha;
            float ps = 0.f;
#pragma unroll
            for (int nt = 0; nt < 4; nt++) {
                const float e = __expf(acc_s[nt][r] - m_new);
                acc_s[nt][r] = e;
                ps += e;
            }
            p_sum[r] = ps;
        }
#pragma unroll
        for (int r = 0; r < 4; r++) {
            float ps = p_sum[r];
#pragma unroll
            for (int off = 1; off < 16; off <<= 1) ps += __shfl_xor(ps, off);
            l_i[r] += ps;
        }

#pragma unroll
        for (int nt = 0; nt < 4; nt++)
#pragma unroll
            for (int r = 0; r < 4; r++)
                Ps[w][(quad << 2) + r][(nt << 4) + col] = f2bf(acc_s[nt][r]);

        bf16x8 pf0 = *(const bf16x8*)&Ps[w][col][quad << 3];
        bf16x8 pf1 = *(const bf16x8*)&Ps[w][col][32 + (quad << 3)];
#pragma unroll
        for (int nt = 0; nt < 4; nt++) {
            union { bf16x8 v; u16 e[8]; } vf0, vf1;
#pragma unroll
            for (int j = 0; j < 8; j++) {
                vf0.e[j] = Vs[(quad << 3) + j][(nt << 4) + col];
                vf1.e[j] = Vs[32 + (quad << 3) + j][(nt << 4) + col];
            }
            acc_o[nt] = __builtin_amdgcn_mfma_f32_16x16x32_bf16(pf0, vf0.v, acc_o[nt], 0, 0, 0);
            acc_o[nt] = __builtin_amdgcn_mfma_f32_16x16x32_bf16(pf1, vf1.v, acc_o[nt], 0, 0, 0);
        }
        __syncthreads();
    }

    const size_t obase = (size_t)blockIdx.x * GG * DD;
#pragma unroll
    for (int nt = 0; nt < 4; nt++) {
#pragma unroll
        for (int r = 0; r < 4; r++) {
            const int row = (w << 4) + (quad << 2) + r;
            Op[obase + (size_t)row * DD + (nt << 4) + col] = acc_o[nt][r];
        }
    }
    if (col == 0) {
#pragma unroll
        for (int r = 0; r < 4; r++) {
            const int row = (w << 4) + (quad << 2) + r;
            Ml[blockIdx.x * GG + row] = m_i[r];
            Ll[blockIdx.x * GG + row] = l_i[r];
        }
    }
}

// ---------- combine split-K partials ---------- (unchanged, passing)
__global__ __launch_bounds__(256) void global_combine_kernel(
    const float* __restrict__ Op, const float* __restrict__ Ml, const float* __restrict__ Ll,
    u16* __restrict__ attnb)
{
    const int bh  = blockIdx.x;
    const int b   = bh >> 4;
    const int h   = bh & (HH - 1);
    const int row = threadIdx.x >> 2;
    const int d0  = (threadIdx.x & 3) << 4;

    float mv[NSPLIT];
    float m = -1e30f;
#pragma unroll
    for (int s = 0; s < NSPLIT; s++) {
        mv[s] = Ml[(bh * NSPLIT + s) * GG + row];
        m = fmaxf(m, mv[s]);
    }
    float l = 0.f;
    float sc[NSPLIT];
#pragma unroll
    for (int s = 0; s < NSPLIT; s++) {
        sc[s] = __expf(mv[s] - m);
        l += Ll[(bh * NSPLIT + s) * GG + row] * sc[s];
    }
    float o[16];
#pragma unroll
    for (int j = 0; j < 16; j++) o[j] = 0.f;
#pragma unroll
    for (int s = 0; s < NSPLIT; s++) {
        const float* src = Op + ((size_t)(bh * NSPLIT + s) * GG + row) * DD + d0;
        const float f = sc[s];
#pragma unroll
        for (int j = 0; j < 16; j += 4) {
            const float4 v4 = *(const float4*)(src + j);
            o[j + 0] = fmaf(v4.x, f, o[j + 0]);
            o[j + 1] = fmaf(v4.y, f, o[j + 1]);
            o[j + 2] = fmaf(v4.z, f, o[j + 2]);
            o[j + 3] = fmaf(v4.w, f, o[j + 3]);
        }
    }
    const float inv = 1.f / l;
    u16* dst = attnb + ((size_t)b * TT + row) * EE + (size_t)h * DD + d0;
#pragma unroll
    for (int j = 0; j < 16; j++) dst[j] = f2bf(o[j] * inv);
}

extern "C" void kernel_launch(void* const* d_in, const int* in_sizes, int n_in,
                              void* d_out, int out_size, void* d_ws, size_t ws_size,
                              hipStream_t stream)
{
    (void)in_sizes; (void)n_in; (void)out_size; (void)ws_size;
    const float* query = (const float*)d_in[0];
    const float* Wq  = (const float*)d_in[2];  const float* bq  = (const float*)d_in[3];
    const float* Wk  = (const float*)d_in[4];  const float* bk  = (const float*)d_in[5];
    const float* Wv  = (const float*)d_in[6];  const float* bv  = (const float*)d_in[7];
    const float* Wqg = (const float*)d_in[8];  const float* bqg = (const float*)d_in[9];
    const float* Wkg = (const float*)d_in[10]; const float* bkg = (const float*)d_in[11];
    const float* Wvg = (const float*)d_in[12]; const float* bvg = (const float*)d_in[13];
    const float* Wo  = (const float*)d_in[14]; const float* bo  = (const float*)d_in[15];

    const size_t nfull = (size_t)BBATCH * TT * EE;      // 8.39M elems
    const size_t wsz   = (size_t)1 << 20;               // one weight, elems
    u16* xb    = (u16*)d_ws;                            // bf16 x [B,T,E]; later reused as attnb
    u16* wb    = xb + nfull;                            // 7 converted weights
    u16* slotA = wb + 7 * wsz;                          // kg, then q
    u16* slotB = slotA + nfull;                         // vg, then k
    u16* slotC = slotB + nfull;                         // vt [B,H,D,T]
    u16* qg    = slotC + nfull;                         // [B*G, E]
    float* Op  = (float*)(qg + (size_t)BBATCH * GG * EE);
    float* Ml  = Op + (size_t)BBATCH * HH * NSPLIT * GG * DD;
    float* Ll  = Ml + (size_t)BBATCH * HH * NSPLIT * GG;
    u16* attnb = xb;                                    // alias: xb dead after last proj GEMM
    // peak ws ≈ 86 MB

    WPtrs wp;
    wp.p[0] = Wq; wp.p[1] = Wk; wp.p[2] = Wv; wp.p[3] = Wqg;
    wp.p[4] = Wkg; wp.p[5] = Wvg; wp.p[6] = Wo;

    const dim3 blk(256);
    const dim3 gFull(EE / 128, (BBATCH * TT) / 128);
    const dim3 gQg(EE / 128, 1);
    const float sc = 0.125f;  // D^-0.5

    conv_kernel<<<7680, blk, 0, stream>>>(wp, query, wb, xb);

    // global-path projections first, so their slots can be reused
    gemm_kernel<0,1,0><<<gQg,   blk, 0, stream>>>(xb, wb + 3 * wsz, bqg, qg,    sc);
    gemm_kernel<0,0,0><<<gFull, blk, 0, stream>>>(xb, wb + 4 * wsz, bkg, slotA, 1.f);
    gemm_kernel<0,0,0><<<gFull, blk, 0, stream>>>(xb, wb + 5 * wsz, bvg, slotB, 1.f);
    global_attn_flash_kernel<<<BBATCH * HH * NSPLIT, blk, 0, stream>>>(qg, slotA, slotB, Op, Ml, Ll);

    gemm_kernel<0,0,0><<<gFull, blk, 0, stream>>>(xb, wb + 0 * wsz, bq, slotA, sc);
    gemm_kernel<0,0,0><<<gFull, blk, 0, stream>>>(xb, wb + 1 * wsz, bk, slotB, 1.f);
    gemm_kernel<0,0,2><<<gFull, blk, 0, stream>>>(xb, wb + 2 * wsz, bv, slotC, 1.f);   // V transposed per head

    band_attn_kernel<<<BBATCH * HH * (TT / 64), blk, 0, stream>>>(slotA, slotB, slotC, attnb);
    global_combine_kernel<<<BBATCH * HH, blk, 0, stream>>>(Op, Ml, Ll, attnb);

    gemm_kernel<1,0,1><<<gFull, blk, 0, stream>>>(attnb, wb + 6 * wsz, bo, (void*)d_out, 1.f);
}

// Round 7
// 398.821 us; speedup vs baseline: 1.2329x; 1.2329x over previous
//
#include <hip/hip_runtime.h>
#include <hip/hip_bf16.h>

typedef unsigned short u16;
typedef __bf16 bf16x8 __attribute__((ext_vector_type(8)));
typedef float  f32x4  __attribute__((ext_vector_type(4)));

constexpr int TT = 4096;   // seq
constexpr int BBATCH = 2;  // batch
constexpr int EE = 1024;   // embed
constexpr int HH = 16;     // heads
constexpr int DD = 64;     // head dim
constexpr int WQ = 256;    // one-sided window
constexpr int GG = 64;     // global tokens
constexpr int NSPLIT = 8;  // key splits for global attention

// ---------- bf16 helpers ----------
__device__ __forceinline__ u16 f2bf(float f) {
    union { float f; unsigned int i; } c; c.f = f;
    unsigned int x = c.i;
    return (u16)((x + 0x7fffu + ((x >> 16) & 1u)) >> 16);  // RNE
}
__device__ __forceinline__ uint4 pack8(float4 a, float4 b) {
    uint4 r;
    r.x = (unsigned)f2bf(a.x) | ((unsigned)f2bf(a.y) << 16);
    r.y = (unsigned)f2bf(a.z) | ((unsigned)f2bf(a.w) << 16);
    r.z = (unsigned)f2bf(b.x) | ((unsigned)f2bf(b.y) << 16);
    r.w = (unsigned)f2bf(b.z) | ((unsigned)f2bf(b.w) << 16);
    return r;
}

// async global->LDS, 16B per lane; LDS dest = wave-uniform base + lane*16
__device__ __forceinline__ void g2l16(const u16* g, u16* l) {
    __builtin_amdgcn_global_load_lds(
        (const __attribute__((address_space(1))) void*)g,
        (__attribute__((address_space(3))) void*)l, 16, 0, 0);
}

// ---------- fp32 -> bf16 conversion ----------
// weight order: Wq,Wk,Wv (fuse3) | Wkg,Wvg (fuse2) | Wqg | Wo ; then query perm [T,B,E]->[B,T,E]
struct WPtrs { const float* p[7]; };
__global__ __launch_bounds__(256) void conv_kernel(
    WPtrs wp, const float* __restrict__ query, u16* __restrict__ wb, u16* __restrict__ xb)
{
    const size_t i8 = ((size_t)blockIdx.x * 256 + threadIdx.x) << 3;
    const size_t WTOT = (size_t)7 << 20;   // 7 x 1024*1024
    const float* src;
    u16* dst;
    if (i8 < WTOT) {
        const int which = (int)(i8 >> 20);
        src = wp.p[which] + (i8 & (((size_t)1 << 20) - 1));
        dst = wb + i8;
    } else {
        const size_t j = i8 - WTOT;            // dst index in [B,T,E]
        const size_t e = j & (EE - 1);
        const size_t t = (j >> 10) & (TT - 1);
        const size_t b = j >> 22;
        src = query + (t * BBATCH + b) * EE + e;
        dst = xb + j;
    }
    const float4 f0 = *(const float4*)src;
    const float4 f1 = *(const float4*)(src + 4);
    *(uint4*)dst = pack8(f0, f1);
}

// ---------- single-output GEMM (qg and Wo): C = (A @ W^T + bias) * scale ----------
// PERMA_QG: logical row m reads source row (m>>6)*4096 + (m&63)  (x[:, :G] gather)
// PERMC_TB: store row m=b*T+t to row t*2+b ([B,T]->[T,B])
template<int C_F32, int PERMA_QG, int PERMC_TB>
__global__ __launch_bounds__(256) void gemm_kernel(
    const u16* __restrict__ A, const u16* __restrict__ W, const float* __restrict__ bias,
    void* __restrict__ Cv, float scale)
{
    const int tid = threadIdx.x, lane = tid & 63, w = tid >> 6;
    const int wm = w >> 1, wn = w & 1;
    const int m0 = blockIdx.y << 7, n0 = blockIdx.x << 7;

    __shared__ __align__(16) u16 As[128 * 32];
    __shared__ __align__(16) u16 Bs[128 * 32];

    const int lrow = lane >> 2;
    const int lcol = (lane & 3) << 3;
    auto arow = [](int m) -> size_t {
        return PERMA_QG ? (size_t)(((m >> 6) << 12) | (m & 63)) : (size_t)m;
    };
    const u16* gA0 = A + arow(m0 + (w << 4) + lrow) * EE + lcol;
    const u16* gA1 = A + arow(m0 + 64 + (w << 4) + lrow) * EE + lcol;
    const u16* gB0 = W + (size_t)(n0 + (w << 4) + lrow) * EE + lcol;
    const u16* gB1 = gB0 + (size_t)64 * EE;
    u16* lA0 = As + (w << 9);
    u16* lA1 = As + 2048 + (w << 9);
    u16* lB0 = Bs + (w << 9);
    u16* lB1 = Bs + 2048 + (w << 9);

    f32x4 acc[4][4];
#pragma unroll
    for (int i = 0; i < 4; i++)
#pragma unroll
        for (int j = 0; j < 4; j++)
            acc[i][j] = (f32x4){0.f, 0.f, 0.f, 0.f};

    const int fr = lane & 15;
    const int fq = (lane >> 4) << 3;

    for (int k0 = 0; k0 < EE; k0 += 32) {
        g2l16(gA0 + k0, lA0);
        g2l16(gA1 + k0, lA1);
        g2l16(gB0 + k0, lB0);
        g2l16(gB1 + k0, lB1);
        __syncthreads();
        bf16x8 af[4], bfv[4];
#pragma unroll
        for (int i = 0; i < 4; i++)
            af[i] = *(const bf16x8*)&As[((wm << 6) + (i << 4) + fr) * 32 + fq];
#pragma unroll
        for (int j = 0; j < 4; j++)
            bfv[j] = *(const bf16x8*)&Bs[((wn << 6) + (j << 4) + fr) * 32 + fq];
#pragma unroll
        for (int i = 0; i < 4; i++)
#pragma unroll
            for (int j = 0; j < 4; j++)
                acc[i][j] = __builtin_amdgcn_mfma_f32_16x16x32_bf16(af[i], bfv[j], acc[i][j], 0, 0, 0);
        __syncthreads();
    }

    const int colbase = n0 + (wn << 6);
    const int rowbase = m0 + (wm << 6) + ((lane >> 4) << 2);
#pragma unroll
    for (int j = 0; j < 4; j++) {
        const int col = colbase + (j << 4) + fr;
        const float bv = bias[col];
#pragma unroll
        for (int i = 0; i < 4; i++) {
#pragma unroll
            for (int r = 0; r < 4; r++) {
                const int row = rowbase + (i << 4) + r;
                const float val = (acc[i][j][r] + bv) * scale;
                const size_t dst = (size_t)(PERMC_TB ? (((row & (TT - 1)) << 1) | (row >> 12)) : row) * EE + col;
                if (C_F32) ((float*)Cv)[dst] = val;
                else       ((u16*)Cv)[dst]   = f2bf(val);
            }
        }
    }
}

// ---------- fused multi-output GEMM: NSEG 1024-col segments, per-segment out/bias/scale ----------
// segment vseg stores V transposed per head: vt[((b*H+h)*64+d)*T + t], ushort4 along t.
struct FusedArgs { u16* out[3]; const float* bias[3]; float scale[3]; int vseg; };
template<int NSEG>
__global__ __launch_bounds__(256) void gemm_fused_kernel(
    const u16* __restrict__ A, const u16* __restrict__ W, FusedArgs fa)
{
    const int tid = threadIdx.x, lane = tid & 63, w = tid >> 6;
    const int wm = w >> 1, wn = w & 1;
    const int m0 = blockIdx.y << 7, n0 = blockIdx.x << 7;

    __shared__ __align__(16) u16 As[128 * 32];
    __shared__ __align__(16) u16 Bs[128 * 32];

    const int lrow = lane >> 2;
    const int lcol = (lane & 3) << 3;
    const u16* gA0 = A + (size_t)(m0 + (w << 4) + lrow) * EE + lcol;
    const u16* gA1 = gA0 + (size_t)64 * EE;
    const u16* gB0 = W + (size_t)(n0 + (w << 4) + lrow) * EE + lcol;
    const u16* gB1 = gB0 + (size_t)64 * EE;
    u16* lA0 = As + (w << 9);
    u16* lA1 = As + 2048 + (w << 9);
    u16* lB0 = Bs + (w << 9);
    u16* lB1 = Bs + 2048 + (w << 9);

    f32x4 acc[4][4];
#pragma unroll
    for (int i = 0; i < 4; i++)
#pragma unroll
        for (int j = 0; j < 4; j++)
            acc[i][j] = (f32x4){0.f, 0.f, 0.f, 0.f};

    const int fr = lane & 15;
    const int fq = (lane >> 4) << 3;

    for (int k0 = 0; k0 < EE; k0 += 32) {
        g2l16(gA0 + k0, lA0);
        g2l16(gA1 + k0, lA1);
        g2l16(gB0 + k0, lB0);
        g2l16(gB1 + k0, lB1);
        __syncthreads();
        bf16x8 af[4], bfv[4];
#pragma unroll
        for (int i = 0; i < 4; i++)
            af[i] = *(const bf16x8*)&As[((wm << 6) + (i << 4) + fr) * 32 + fq];
#pragma unroll
        for (int j = 0; j < 4; j++)
            bfv[j] = *(const bf16x8*)&Bs[((wn << 6) + (j << 4) + fr) * 32 + fq];
#pragma unroll
        for (int i = 0; i < 4; i++)
#pragma unroll
            for (int j = 0; j < 4; j++)
                acc[i][j] = __builtin_amdgcn_mfma_f32_16x16x32_bf16(af[i], bfv[j], acc[i][j], 0, 0, 0);
        __syncthreads();
    }

    const int seg = n0 >> 10;                  // uniform per block (128 | 1024)
    u16* outp = fa.out[seg];
    const float* bp = fa.bias[seg];
    const float scl = fa.scale[seg];
    const bool vtr = (seg == fa.vseg);

    const int colbase = n0 + (wn << 6);
    const int rowbase = m0 + (wm << 6) + ((lane >> 4) << 2);
#pragma unroll
    for (int j = 0; j < 4; j++) {
        const int col = colbase + (j << 4) + fr;
        const int cl  = col & (EE - 1);        // col within segment
        const float bv = bp[cl];
#pragma unroll
        for (int i = 0; i < 4; i++) {
            if (vtr) {
                const int row0 = rowbase + (i << 4);      // t multiple of 4
                const int bb = row0 >> 12, t = row0 & (TT - 1);
                const int hh = cl >> 6, d = cl & 63;
                ushort4 pk;
                pk.x = f2bf((acc[i][j][0] + bv) * scl);
                pk.y = f2bf((acc[i][j][1] + bv) * scl);
                pk.z = f2bf((acc[i][j][2] + bv) * scl);
                pk.w = f2bf((acc[i][j][3] + bv) * scl);
                *(ushort4*)(outp + (((size_t)(bb * HH + hh) * DD + d) * TT + t)) = pk;
            } else {
#pragma unroll
                for (int r = 0; r < 4; r++) {
                    const int row = rowbase + (i << 4) + r;
                    outp[(size_t)row * EE + cl] = f2bf((acc[i][j][r] + bv) * scl);
                }
            }
        }
    }
}

// ---------- band attention, MFMA flash (r5 staged structure + vt staging + chunk skip) ----------
// blockIdx.x = qt*32 + (b*H+h) (XCD slab locality). K staged [key][dim] stride 72;
// V staged [dim][key] stride 72 from pre-transposed vt (coalesced rows). Q frags direct global.
__global__ __launch_bounds__(256) void band_attn_kernel(
    const u16* __restrict__ q, const u16* __restrict__ k, const u16* __restrict__ vt,
    u16* __restrict__ attnb)
{
    const int tid  = threadIdx.x;
    const int lane = tid & 63;
    const int w    = tid >> 6;
    const int col  = lane & 15;
    const int quad = lane >> 4;

    const int qt = blockIdx.x >> 5;
    const int bh = blockIdx.x & 31;
    const int h  = bh & (HH - 1);
    const int b  = bh >> 4;
    const int t0 = qt << 6;

    __shared__ __align__(16) u16 Ks[64][72];   // [key][dim]
    __shared__ __align__(16) u16 Vs[64][72];   // [dim][key]
    __shared__ __align__(16) u16 Ps[4][16][72];

    const size_t base   = (size_t)b * TT * EE + (size_t)h * DD;
    const size_t vtbase = (size_t)bh * DD * TT;

    // Q fragments: direct global load, held in regs for whole kernel
    const u16* qp = q + base + (size_t)(t0 + (w << 4) + col) * EE + (quad << 3);
    const bf16x8 qf0 = *(const bf16x8*)qp;
    const bf16x8 qf1 = *(const bf16x8*)(qp + 32);

    float m_i[4], l_i[4];
    f32x4 acc_o[4];
#pragma unroll
    for (int r = 0; r < 4; r++) { m_i[r] = -1e30f; l_i[r] = 0.f; }
#pragma unroll
    for (int nt = 0; nt < 4; nt++) acc_o[nt] = (f32x4){0.f, 0.f, 0.f, 0.f};

    const int c_lo = 1 + ((t0 < WQ) ? ((WQ - t0) >> 6) : 0);
    const int c_hi = min(9, 1 + ((TT + WQ - 64 - t0) >> 6));

    const int srow  = tid >> 2;           // staging row (key for Ks, dim for Vs)
    const int spart = (tid & 3) << 4;

    auto process = [&](int kpos0, int jbase) {   // jbase >= 0 -> window mask
        // ---- stage K [key][dim] and V [dim][key] (both in-range by skip) ----
        {
            const u16* ks = k + base + (size_t)(kpos0 + srow) * EE + spart;
            const u16* vs = vt + vtbase + (size_t)srow * TT + kpos0 + spart;
            const uint4 k0v = *(const uint4*)ks;
            const uint4 k1v = *(const uint4*)(ks + 8);
            const uint4 v0v = *(const uint4*)vs;
            const uint4 v1v = *(const uint4*)(vs + 8);
            *(uint4*)&Ks[srow][spart]     = k0v;
            *(uint4*)&Ks[srow][spart + 8] = k1v;
            *(uint4*)&Vs[srow][spart]     = v0v;
            *(uint4*)&Vs[srow][spart + 8] = v1v;
        }
        __syncthreads();

        // ---- QK^T ----
        f32x4 acc_s[4];
#pragma unroll
        for (int nt = 0; nt < 4; nt++) {
            const bf16x8 kf0 = *(const bf16x8*)&Ks[(nt << 4) + col][quad << 3];
            const bf16x8 kf1 = *(const bf16x8*)&Ks[(nt << 4) + col][32 + (quad << 3)];
            f32x4 s = (f32x4){0.f, 0.f, 0.f, 0.f};
            s = __builtin_amdgcn_mfma_f32_16x16x32_bf16(qf0, kf0, s, 0, 0, 0);
            s = __builtin_amdgcn_mfma_f32_16x16x32_bf16(qf1, kf1, s, 0, 0, 0);
            acc_s[nt] = s;
        }

        if (jbase >= 0) {
#pragma unroll
            for (int nt = 0; nt < 4; nt++) {
#pragma unroll
                for (int r = 0; r < 4; r++) {
                    const int jp   = jbase + (nt << 4) + col;
                    const int qrow = (w << 4) + (quad << 2) + r;
                    const bool ok  = (jp >= qrow) && (jp <= qrow + 2 * WQ);
                    if (!ok) acc_s[nt][r] = -1e30f;
                }
            }
        }

        // ---- online softmax ----
        float p_sum[4];
#pragma unroll
        for (int r = 0; r < 4; r++) {
            float mx = fmaxf(fmaxf(acc_s[0][r], acc_s[1][r]), fmaxf(acc_s[2][r], acc_s[3][r]));
#pragma unroll
            for (int off = 1; off < 16; off <<= 1) mx = fmaxf(mx, __shfl_xor(mx, off));
            const float m_new = fmaxf(m_i[r], mx);
            const float alpha = __expf(m_i[r] - m_new);
            m_i[r] = m_new;
            l_i[r] *= alpha;
#pragma unroll
            for (int nt = 0; nt < 4; nt++) acc_o[nt][r] *= alpha;
            float ps = 0.f;
#pragma unroll
            for (int nt = 0; nt < 4; nt++) {
                const float e = __expf(acc_s[nt][r] - m_new);
                acc_s[nt][r] = e;
                ps += e;
            }
            p_sum[r] = ps;
        }
#pragma unroll
        for (int r = 0; r < 4; r++) {
            float ps = p_sum[r];
#pragma unroll
            for (int off = 1; off < 16; off <<= 1) ps += __shfl_xor(ps, off);
            l_i[r] += ps;
        }

        // ---- P: C-layout -> per-wave LDS -> A-layout ----
#pragma unroll
        for (int nt = 0; nt < 4; nt++)
#pragma unroll
            for (int r = 0; r < 4; r++)
                Ps[w][(quad << 2) + r][(nt << 4) + col] = f2bf(acc_s[nt][r]);

        const bf16x8 pf0 = *(const bf16x8*)&Ps[w][col][quad << 3];
        const bf16x8 pf1 = *(const bf16x8*)&Ps[w][col][32 + (quad << 3)];

        // ---- PV: B-frag from Vs[dim][key], same conflict-free pattern as Ks ----
#pragma unroll
        for (int nt = 0; nt < 4; nt++) {
            const bf16x8 vf0 = *(const bf16x8*)&Vs[(nt << 4) + col][quad << 3];
            const bf16x8 vf1 = *(const bf16x8*)&Vs[(nt << 4) + col][32 + (quad << 3)];
            acc_o[nt] = __builtin_amdgcn_mfma_f32_16x16x32_bf16(pf0, vf0, acc_o[nt], 0, 0, 0);
            acc_o[nt] = __builtin_amdgcn_mfma_f32_16x16x32_bf16(pf1, vf1, acc_o[nt], 0, 0, 0);
        }
        __syncthreads();
    };

    process(0, -1);                                   // global keys [0,64), unmasked
#pragma unroll 1
    for (int c = c_lo; c <= c_hi; c++) {
        const int kpos0 = t0 - WQ + ((c - 1) << 6);
        const bool edge = (c == 1) || (c == 9);       // only partial-window chunks need mask
        process(kpos0, edge ? ((c - 1) << 6) : -1);
    }

    float inv[4];
#pragma unroll
    for (int r = 0; r < 4; r++) inv[r] = 1.f / l_i[r];
#pragma unroll
    for (int nt = 0; nt < 4; nt++) {
#pragma unroll
        for (int r = 0; r < 4; r++) {
            const int t = t0 + (w << 4) + (quad << 2) + r;
            attnb[base + (size_t)t * EE + (nt << 4) + col] = f2bf(acc_o[nt][r] * inv[r]);
        }
    }
}

// ---------- global-token attention, MFMA flash + split-K ---------- (unchanged, passing)
__global__ __launch_bounds__(256) void global_attn_flash_kernel(
    const u16* __restrict__ qg, const u16* __restrict__ kg, const u16* __restrict__ vg,
    float* __restrict__ Op, float* __restrict__ Ml, float* __restrict__ Ll)
{
    const int tid  = threadIdx.x;
    const int lane = tid & 63;
    const int w    = tid >> 6;
    const int col  = lane & 15;
    const int quad = lane >> 4;

    const int s  = blockIdx.x & (NSPLIT - 1);
    const int h  = (blockIdx.x >> 3) & (HH - 1);
    const int b  = blockIdx.x >> 7;
    const int k0pos = s * (TT / NSPLIT);

    __shared__ __align__(16) u16 Qs[64][72];
    __shared__ __align__(16) u16 Ks[64][72];
    __shared__ __align__(16) u16 Vs[64][70];
    __shared__ __align__(16) u16 Ps[4][16][72];

    const size_t base = (size_t)b * TT * EE + (size_t)h * DD;

    {
        const int qr   = tid >> 2;
        const int part = (tid & 3) << 4;
        const uint4* src = (const uint4*)(qg + (size_t)(b * GG + qr) * EE + (size_t)h * DD + part);
        *(uint4*)&Qs[qr][part]     = src[0];
        *(uint4*)&Qs[qr][part + 8] = src[1];
    }

    float m_i[4], l_i[4];
    f32x4 acc_o[4];
#pragma unroll
    for (int r = 0; r < 4; r++) { m_i[r] = -1e30f; l_i[r] = 0.f; }
#pragma unroll
    for (int nt = 0; nt < 4; nt++) acc_o[nt] = (f32x4){0.f, 0.f, 0.f, 0.f};

#pragma unroll 1
    for (int cc = 0; cc < TT / NSPLIT / 64; cc++) {
        {
            const int kk   = tid >> 2;
            const int part = (tid & 3) << 4;
            const int pos  = k0pos + (cc << 6) + kk;
            const uint4* ks = (const uint4*)(kg + base + (size_t)pos * EE + part);
            const uint4* vs = (const uint4*)(vg + base + (size_t)pos * EE + part);
            const uint4 k0v = ks[0], k1v = ks[1];
            const uint4 v0v = vs[0], v1v = vs[1];
            *(uint4*)&Ks[kk][part]     = k0v;
            *(uint4*)&Ks[kk][part + 8] = k1v;
            unsigned int* vd = (unsigned int*)&Vs[kk][part];
            vd[0] = v0v.x; vd[1] = v0v.y; vd[2] = v0v.z; vd[3] = v0v.w;
            vd[4] = v1v.x; vd[5] = v1v.y; vd[6] = v1v.z; vd[7] = v1v.w;
        }
        __syncthreads();

        bf16x8 qf0 = *(const bf16x8*)&Qs[(w << 4) + col][quad << 3];
        bf16x8 qf1 = *(const bf16x8*)&Qs[(w << 4) + col][32 + (quad << 3)];
        f32x4 acc_s[4];
#pragma unroll
        for (int nt = 0; nt < 4; nt++) {
            bf16x8 kf0 = *(const bf16x8*)&Ks[(nt << 4) + col][quad << 3];
            bf16x8 kf1 = *(const bf16x8*)&Ks[(nt << 4) + col][32 + (quad << 3)];
            f32x4 sv = (f32x4){0.f, 0.f, 0.f, 0.f};
            sv = __builtin_amdgcn_mfma_f32_16x16x32_bf16(qf0, kf0, sv, 0, 0, 0);
            sv = __builtin_amdgcn_mfma_f32_16x16x32_bf16(qf1, kf1, sv, 0, 0, 0);
            acc_s[nt] = sv;
        }

        float m_c[4], p_sum[4];
#pragma unroll
        for (int r = 0; r < 4; r++) {
            float mx = fmaxf(fmaxf(acc_s[0][r], acc_s[1][r]), fmaxf(acc_s[2][r], acc_s[3][r]));
#pragma unroll
            for (int off = 1; off < 16; off <<= 1) mx = fmaxf(mx, __shfl_xor(mx, off));
            m_c[r] = mx;
        }
#pragma unroll
        for (int r = 0; r < 4; r++) {
            const float m_new = fmaxf(m_i[r], m_c[r]);
            const float alpha = __expf(m_i[r] - m_new);
            m_i[r] = m_new;
            l_i[r] *= alpha;
#pragma unroll
            for (int nt = 0; nt < 4; nt++) acc_o[nt][r] *= alpha;
            float ps = 0.f;
#pragma unroll
            for (int nt = 0; nt < 4; nt++) {
                const float e = __expf(acc_s[nt][r] - m_new);
                acc_s[nt][r] = e;
                ps += e;
            }
            p_sum[r] = ps;
        }
#pragma unroll
        for (int r = 0; r < 4; r++) {
            float ps = p_sum[r];
#pragma unroll
            for (int off = 1; off < 16; off <<= 1) ps += __shfl_xor(ps, off);
            l_i[r] += ps;
        }

#pragma unroll
        for (int nt = 0; nt < 4; nt++)
#pragma unroll
            for (int r = 0; r < 4; r++)
                Ps[w][(quad << 2) + r][(nt << 4) + col] = f2bf(acc_s[nt][r]);

        bf16x8 pf0 = *(const bf16x8*)&Ps[w][col][quad << 3];
        bf16x8 pf1 = *(const bf16x8*)&Ps[w][col][32 + (quad << 3)];
#pragma unroll
        for (int nt = 0; nt < 4; nt++) {
            union { bf16x8 v; u16 e[8]; } vf0, vf1;
#pragma unroll
            for (int j = 0; j < 8; j++) {
                vf0.e[j] = Vs[(quad << 3) + j][(nt << 4) + col];
                vf1.e[j] = Vs[32 + (quad << 3) + j][(nt << 4) + col];
            }
            acc_o[nt] = __builtin_amdgcn_mfma_f32_16x16x32_bf16(pf0, vf0.v, acc_o[nt], 0, 0, 0);
            acc_o[nt] = __builtin_amdgcn_mfma_f32_16x16x32_bf16(pf1, vf1.v, acc_o[nt], 0, 0, 0);
        }
        __syncthreads();
    }

    const size_t obase = (size_t)blockIdx.x * GG * DD;
#pragma unroll
    for (int nt = 0; nt < 4; nt++) {
#pragma unroll
        for (int r = 0; r < 4; r++) {
            const int row = (w << 4) + (quad << 2) + r;
            Op[obase + (size_t)row * DD + (nt << 4) + col] = acc_o[nt][r];
        }
    }
    if (col == 0) {
#pragma unroll
        for (int r = 0; r < 4; r++) {
            const int row = (w << 4) + (quad << 2) + r;
            Ml[blockIdx.x * GG + row] = m_i[r];
            Ll[blockIdx.x * GG + row] = l_i[r];
        }
    }
}

// ---------- combine split-K partials ---------- (unchanged, passing)
__global__ __launch_bounds__(256) void global_combine_kernel(
    const float* __restrict__ Op, const float* __restrict__ Ml, const float* __restrict__ Ll,
    u16* __restrict__ attnb)
{
    const int bh  = blockIdx.x;
    const int b   = bh >> 4;
    const int h   = bh & (HH - 1);
    const int row = threadIdx.x >> 2;
    const int d0  = (threadIdx.x & 3) << 4;

    float mv[NSPLIT];
    float m = -1e30f;
#pragma unroll
    for (int s = 0; s < NSPLIT; s++) {
        mv[s] = Ml[(bh * NSPLIT + s) * GG + row];
        m = fmaxf(m, mv[s]);
    }
    float l = 0.f;
    float sc[NSPLIT];
#pragma unroll
    for (int s = 0; s < NSPLIT; s++) {
        sc[s] = __expf(mv[s] - m);
        l += Ll[(bh * NSPLIT + s) * GG + row] * sc[s];
    }
    float o[16];
#pragma unroll
    for (int j = 0; j < 16; j++) o[j] = 0.f;
#pragma unroll
    for (int s = 0; s < NSPLIT; s++) {
        const float* src = Op + ((size_t)(bh * NSPLIT + s) * GG + row) * DD + d0;
        const float f = sc[s];
#pragma unroll
        for (int j = 0; j < 16; j += 4) {
            const float4 v4 = *(const float4*)(src + j);
            o[j + 0] = fmaf(v4.x, f, o[j + 0]);
            o[j + 1] = fmaf(v4.y, f, o[j + 1]);
            o[j + 2] = fmaf(v4.z, f, o[j + 2]);
            o[j + 3] = fmaf(v4.w, f, o[j + 3]);
        }
    }
    const float inv = 1.f / l;
    u16* dst = attnb + ((size_t)b * TT + row) * EE + (size_t)h * DD + d0;
#pragma unroll
    for (int j = 0; j < 16; j++) dst[j] = f2bf(o[j] * inv);
}

extern "C" void kernel_launch(void* const* d_in, const int* in_sizes, int n_in,
                              void* d_out, int out_size, void* d_ws, size_t ws_size,
                              hipStream_t stream)
{
    (void)in_sizes; (void)n_in; (void)out_size; (void)ws_size;
    const float* query = (const float*)d_in[0];
    const float* Wq  = (const float*)d_in[2];  const float* bq  = (const float*)d_in[3];
    const float* Wk  = (const float*)d_in[4];  const float* bk  = (const float*)d_in[5];
    const float* Wv  = (const float*)d_in[6];  const float* bv  = (const float*)d_in[7];
    const float* Wqg = (const float*)d_in[8];  const float* bqg = (const float*)d_in[9];
    const float* Wkg = (const float*)d_in[10]; const float* bkg = (const float*)d_in[11];
    const float* Wvg = (const float*)d_in[12]; const float* bvg = (const float*)d_in[13];
    const float* Wo  = (const float*)d_in[14]; const float* bo  = (const float*)d_in[15];

    const size_t nfull = (size_t)BBATCH * TT * EE;      // 8.39M elems
    const size_t wsz   = (size_t)1 << 20;               // one weight, elems
    u16* xb    = (u16*)d_ws;                            // bf16 x [B,T,E]; later reused as attnb
    u16* wb    = xb + nfull;                            // 7 converted weights
    u16* slotA = wb + 7 * wsz;                          // kg, then q
    u16* slotB = slotA + nfull;                         // vg, then k
    u16* slotC = slotB + nfull;                         // vt [B,H,D,T]
    u16* qg    = slotC + nfull;                         // [B*G, E]
    float* Op  = (float*)(qg + (size_t)BBATCH * GG * EE);
    float* Ml  = Op + (size_t)BBATCH * HH * NSPLIT * GG * DD;
    float* Ll  = Ml + (size_t)BBATCH * HH * NSPLIT * GG;
    u16* attnb = xb;                                    // alias: xb dead after last GEMM that reads it
    // peak ws ≈ 86 MB

    WPtrs wp;   // order: fuse3 (Wq,Wk,Wv) | fuse2 (Wkg,Wvg) | Wqg | Wo
    wp.p[0] = Wq; wp.p[1] = Wk; wp.p[2] = Wv;
    wp.p[3] = Wkg; wp.p[4] = Wvg; wp.p[5] = Wqg; wp.p[6] = Wo;

    const dim3 blk(256);
    const dim3 gF2(16, 64);     // N=2048
    const dim3 gF3(24, 64);     // N=3072
    const dim3 gFull(8, 64);    // N=1024
    const dim3 gQg(8, 1);
    const float sc = 0.125f;    // D^-0.5

    conv_kernel<<<7680, blk, 0, stream>>>(wp, query, wb, xb);

    // qg projection (reads xb)
    gemm_kernel<0, 1, 0><<<gQg, blk, 0, stream>>>(xb, wb + 5 * wsz, bqg, qg, sc);

    // fused kg|vg projection, then flash (frees slotA/slotB)
    FusedArgs fa2;
    fa2.out[0] = slotA; fa2.out[1] = slotB; fa2.out[2] = nullptr;
    fa2.bias[0] = bkg;  fa2.bias[1] = bvg;  fa2.bias[2] = nullptr;
    fa2.scale[0] = 1.f; fa2.scale[1] = 1.f; fa2.scale[2] = 1.f;
    fa2.vseg = -1;
    gemm_fused_kernel<2><<<gF2, blk, 0, stream>>>(xb, wb + 3 * wsz, fa2);
    global_attn_flash_kernel<<<BBATCH * HH * NSPLIT, blk, 0, stream>>>(qg, slotA, slotB, Op, Ml, Ll);

    // fused q|k|vt projection
    FusedArgs fa3;
    fa3.out[0] = slotA; fa3.out[1] = slotB; fa3.out[2] = slotC;
    fa3.bias[0] = bq;   fa3.bias[1] = bk;   fa3.bias[2] = bv;
    fa3.scale[0] = sc;  fa3.scale[1] = 1.f; fa3.scale[2] = 1.f;
    fa3.vseg = 2;
    gemm_fused_kernel<3><<<gF3, blk, 0, stream>>>(xb, wb, fa3);

    band_attn_kernel<<<BBATCH * HH * (TT / 64), blk, 0, stream>>>(slotA, slotB, slotC, attnb);
    global_combine_kernel<<<BBATCH * HH, blk, 0, stream>>>(Op, Ml, Ll, attnb);

    gemm_kernel<1, 0, 1><<<gFull, blk, 0, stream>>>(attnb, wb + 6 * wsz, bo, (void*)d_out, 1.f);
}

// Round 8
// 374.655 us; speedup vs baseline: 1.3124x; 1.0645x over previous
//
#include <hip/hip_runtime.h>
#include <hip/hip_bf16.h>

typedef unsigned short u16;
typedef __bf16 bf16x8 __attribute__((ext_vector_type(8)));
typedef float  f32x4  __attribute__((ext_vector_type(4)));

constexpr int TT = 4096;   // seq
constexpr int BBATCH = 2;  // batch
constexpr int EE = 1024;   // embed
constexpr int HH = 16;     // heads
constexpr int DD = 64;     // head dim
constexpr int WQ = 256;    // one-sided window
constexpr int GG = 64;     // global tokens
constexpr int NSPLIT = 8;  // key splits for global attention

// ---------- bf16 helpers ----------
__device__ __forceinline__ u16 f2bf(float f) {
    union { float f; unsigned int i; } c; c.f = f;
    unsigned int x = c.i;
    return (u16)((x + 0x7fffu + ((x >> 16) & 1u)) >> 16);  // RNE
}
__device__ __forceinline__ uint4 pack8(float4 a, float4 b) {
    uint4 r;
    r.x = (unsigned)f2bf(a.x) | ((unsigned)f2bf(a.y) << 16);
    r.y = (unsigned)f2bf(a.z) | ((unsigned)f2bf(a.w) << 16);
    r.z = (unsigned)f2bf(b.x) | ((unsigned)f2bf(b.y) << 16);
    r.w = (unsigned)f2bf(b.z) | ((unsigned)f2bf(b.w) << 16);
    return r;
}

// async global->LDS, 16B per lane; LDS dest = wave-uniform base + lane*16
__device__ __forceinline__ void g2l16(const u16* g, u16* l) {
    __builtin_amdgcn_global_load_lds(
        (const __attribute__((address_space(1))) void*)g,
        (__attribute__((address_space(3))) void*)l, 16, 0, 0);
}

// XCD swizzle: blocks sharing an M-tile (y) get linear ids == c (mod 8) -> one XCD's L2
// keeps the A-slab hot. Requires gridDim.y % 8 == 0; falls back to identity otherwise.
__device__ __forceinline__ void xcd_swizzle(int& bx, int& by) {
    bx = blockIdx.x; by = blockIdx.y;
    if ((gridDim.y & 7) == 0) {
        const int g   = blockIdx.x + blockIdx.y * gridDim.x;
        const int idx = g >> 3;
        bx = idx % gridDim.x;
        by = (g & 7) + ((idx / gridDim.x) << 3);
    }
}

// ---------- fp32 -> bf16 conversion ----------
// weight order: Wq,Wk,Wv (fuse3) | Wkg,Wvg (fuse2) | Wqg | Wo ; then query perm [T,B,E]->[B,T,E]
struct WPtrs { const float* p[7]; };
__global__ __launch_bounds__(256) void conv_kernel(
    WPtrs wp, const float* __restrict__ query, u16* __restrict__ wb, u16* __restrict__ xb)
{
    const size_t i8 = ((size_t)blockIdx.x * 256 + threadIdx.x) << 3;
    const size_t WTOT = (size_t)7 << 20;   // 7 x 1024*1024
    const float* src;
    u16* dst;
    if (i8 < WTOT) {
        const int which = (int)(i8 >> 20);
        src = wp.p[which] + (i8 & (((size_t)1 << 20) - 1));
        dst = wb + i8;
    } else {
        const size_t j = i8 - WTOT;            // dst index in [B,T,E]
        const size_t e = j & (EE - 1);
        const size_t t = (j >> 10) & (TT - 1);
        const size_t b = j >> 22;
        src = query + (t * BBATCH + b) * EE + e;
        dst = xb + j;
    }
    const float4 f0 = *(const float4*)src;
    const float4 f1 = *(const float4*)(src + 4);
    *(uint4*)dst = pack8(f0, f1);
}

// ---------- single-output GEMM (qg and Wo): C = (A @ W^T + bias) * scale ----------
// BK=64 via two 32-col panels (one barrier pair per 64 K); XCD swizzle.
// PERMA_QG: logical row m reads source row (m>>6)*4096 + (m&63)  (x[:, :G] gather)
// PERMC_TB: store row m=b*T+t to row t*2+b ([B,T]->[T,B])
template<int C_F32, int PERMA_QG, int PERMC_TB>
__global__ __launch_bounds__(256) void gemm_kernel(
    const u16* __restrict__ A, const u16* __restrict__ W, const float* __restrict__ bias,
    void* __restrict__ Cv, float scale)
{
    const int tid = threadIdx.x, lane = tid & 63, w = tid >> 6;
    const int wm = w >> 1, wn = w & 1;
    int bx, by;
    xcd_swizzle(bx, by);
    const int m0 = by << 7, n0 = bx << 7;

    __shared__ __align__(16) u16 As[2 * 128 * 32];   // two 32-col panels
    __shared__ __align__(16) u16 Bs[2 * 128 * 32];

    const int lrow = lane >> 2;
    const int lcol = (lane & 3) << 3;
    auto arow = [](int m) -> size_t {
        return PERMA_QG ? (size_t)(((m >> 6) << 12) | (m & 63)) : (size_t)m;
    };
    const u16* gA0 = A + arow(m0 + (w << 4) + lrow) * EE + lcol;
    const u16* gA1 = A + arow(m0 + 64 + (w << 4) + lrow) * EE + lcol;
    const u16* gB0 = W + (size_t)(n0 + (w << 4) + lrow) * EE + lcol;
    const u16* gB1 = gB0 + (size_t)64 * EE;
    u16* lA0 = As + (w << 9);
    u16* lA1 = As + 2048 + (w << 9);
    u16* lB0 = Bs + (w << 9);
    u16* lB1 = Bs + 2048 + (w << 9);

    f32x4 acc[4][4];
#pragma unroll
    for (int i = 0; i < 4; i++)
#pragma unroll
        for (int j = 0; j < 4; j++)
            acc[i][j] = (f32x4){0.f, 0.f, 0.f, 0.f};

    const int fr = lane & 15;
    const int fq = (lane >> 4) << 3;

    for (int k0 = 0; k0 < EE; k0 += 64) {
        g2l16(gA0 + k0, lA0);  g2l16(gA0 + k0 + 32, lA0 + 4096);
        g2l16(gA1 + k0, lA1);  g2l16(gA1 + k0 + 32, lA1 + 4096);
        g2l16(gB0 + k0, lB0);  g2l16(gB0 + k0 + 32, lB0 + 4096);
        g2l16(gB1 + k0, lB1);  g2l16(gB1 + k0 + 32, lB1 + 4096);
        __syncthreads();
#pragma unroll
        for (int p = 0; p < 2; p++) {
            bf16x8 af[4], bfv[4];
#pragma unroll
            for (int i = 0; i < 4; i++)
                af[i] = *(const bf16x8*)&As[p * 4096 + ((wm << 6) + (i << 4) + fr) * 32 + fq];
#pragma unroll
            for (int j = 0; j < 4; j++)
                bfv[j] = *(const bf16x8*)&Bs[p * 4096 + ((wn << 6) + (j << 4) + fr) * 32 + fq];
#pragma unroll
            for (int i = 0; i < 4; i++)
#pragma unroll
                for (int j = 0; j < 4; j++)
                    acc[i][j] = __builtin_amdgcn_mfma_f32_16x16x32_bf16(af[i], bfv[j], acc[i][j], 0, 0, 0);
        }
        __syncthreads();
    }

    const int colbase = n0 + (wn << 6);
    const int rowbase = m0 + (wm << 6) + ((lane >> 4) << 2);
#pragma unroll
    for (int j = 0; j < 4; j++) {
        const int col = colbase + (j << 4) + fr;
        const float bv = bias[col];
#pragma unroll
        for (int i = 0; i < 4; i++) {
#pragma unroll
            for (int r = 0; r < 4; r++) {
                const int row = rowbase + (i << 4) + r;
                const float val = (acc[i][j][r] + bv) * scale;
                const size_t dst = (size_t)(PERMC_TB ? (((row & (TT - 1)) << 1) | (row >> 12)) : row) * EE + col;
                if (C_F32) ((float*)Cv)[dst] = val;
                else       ((u16*)Cv)[dst]   = f2bf(val);
            }
        }
    }
}

// ---------- fused multi-output GEMM: NSEG 1024-col segments, per-segment out/bias/scale ----------
// segment vseg stores V transposed per head: vt[((b*H+h)*64+d)*T + t], ushort4 along t.
struct FusedArgs { u16* out[3]; const float* bias[3]; float scale[3]; int vseg; };
template<int NSEG>
__global__ __launch_bounds__(256) void gemm_fused_kernel(
    const u16* __restrict__ A, const u16* __restrict__ W, FusedArgs fa)
{
    const int tid = threadIdx.x, lane = tid & 63, w = tid >> 6;
    const int wm = w >> 1, wn = w & 1;
    int bx, by;
    xcd_swizzle(bx, by);
    const int m0 = by << 7, n0 = bx << 7;

    __shared__ __align__(16) u16 As[2 * 128 * 32];
    __shared__ __align__(16) u16 Bs[2 * 128 * 32];

    const int lrow = lane >> 2;
    const int lcol = (lane & 3) << 3;
    const u16* gA0 = A + (size_t)(m0 + (w << 4) + lrow) * EE + lcol;
    const u16* gA1 = gA0 + (size_t)64 * EE;
    const u16* gB0 = W + (size_t)(n0 + (w << 4) + lrow) * EE + lcol;
    const u16* gB1 = gB0 + (size_t)64 * EE;
    u16* lA0 = As + (w << 9);
    u16* lA1 = As + 2048 + (w << 9);
    u16* lB0 = Bs + (w << 9);
    u16* lB1 = Bs + 2048 + (w << 9);

    f32x4 acc[4][4];
#pragma unroll
    for (int i = 0; i < 4; i++)
#pragma unroll
        for (int j = 0; j < 4; j++)
            acc[i][j] = (f32x4){0.f, 0.f, 0.f, 0.f};

    const int fr = lane & 15;
    const int fq = (lane >> 4) << 3;

    for (int k0 = 0; k0 < EE; k0 += 64) {
        g2l16(gA0 + k0, lA0);  g2l16(gA0 + k0 + 32, lA0 + 4096);
        g2l16(gA1 + k0, lA1);  g2l16(gA1 + k0 + 32, lA1 + 4096);
        g2l16(gB0 + k0, lB0);  g2l16(gB0 + k0 + 32, lB0 + 4096);
        g2l16(gB1 + k0, lB1);  g2l16(gB1 + k0 + 32, lB1 + 4096);
        __syncthreads();
#pragma unroll
        for (int p = 0; p < 2; p++) {
            bf16x8 af[4], bfv[4];
#pragma unroll
            for (int i = 0; i < 4; i++)
                af[i] = *(const bf16x8*)&As[p * 4096 + ((wm << 6) + (i << 4) + fr) * 32 + fq];
#pragma unroll
            for (int j = 0; j < 4; j++)
                bfv[j] = *(const bf16x8*)&Bs[p * 4096 + ((wn << 6) + (j << 4) + fr) * 32 + fq];
#pragma unroll
            for (int i = 0; i < 4; i++)
#pragma unroll
                for (int j = 0; j < 4; j++)
                    acc[i][j] = __builtin_amdgcn_mfma_f32_16x16x32_bf16(af[i], bfv[j], acc[i][j], 0, 0, 0);
        }
        __syncthreads();
    }

    const int seg = n0 >> 10;                  // uniform per block
    u16* outp = fa.out[seg];
    const float* bp = fa.bias[seg];
    const float scl = fa.scale[seg];
    const bool vtr = (seg == fa.vseg);

    const int colbase = n0 + (wn << 6);
    const int rowbase = m0 + (wm << 6) + ((lane >> 4) << 2);
#pragma unroll
    for (int j = 0; j < 4; j++) {
        const int col = colbase + (j << 4) + fr;
        const int cl  = col & (EE - 1);        // col within segment
        const float bv = bp[cl];
#pragma unroll
        for (int i = 0; i < 4; i++) {
            if (vtr) {
                const int row0 = rowbase + (i << 4);      // t multiple of 4
                const int bb = row0 >> 12, t = row0 & (TT - 1);
                const int hh = cl >> 6, d = cl & 63;
                ushort4 pk;
                pk.x = f2bf((acc[i][j][0] + bv) * scl);
                pk.y = f2bf((acc[i][j][1] + bv) * scl);
                pk.z = f2bf((acc[i][j][2] + bv) * scl);
                pk.w = f2bf((acc[i][j][3] + bv) * scl);
                *(ushort4*)(outp + (((size_t)(bb * HH + hh) * DD + d) * TT + t)) = pk;
            } else {
#pragma unroll
                for (int r = 0; r < 4; r++) {
                    const int row = rowbase + (i << 4) + r;
                    outp[(size_t)row * EE + cl] = f2bf((acc[i][j][r] + bv) * scl);
                }
            }
        }
    }
}

// ---------- band attention, MFMA flash ---------- (unchanged from r7, passing)
__global__ __launch_bounds__(256) void band_attn_kernel(
    const u16* __restrict__ q, const u16* __restrict__ k, const u16* __restrict__ vt,
    u16* __restrict__ attnb)
{
    const int tid  = threadIdx.x;
    const int lane = tid & 63;
    const int w    = tid >> 6;
    const int col  = lane & 15;
    const int quad = lane >> 4;

    const int qt = blockIdx.x >> 5;
    const int bh = blockIdx.x & 31;
    const int h  = bh & (HH - 1);
    const int b  = bh >> 4;
    const int t0 = qt << 6;

    __shared__ __align__(16) u16 Ks[64][72];   // [key][dim]
    __shared__ __align__(16) u16 Vs[64][72];   // [dim][key]
    __shared__ __align__(16) u16 Ps[4][16][72];

    const size_t base   = (size_t)b * TT * EE + (size_t)h * DD;
    const size_t vtbase = (size_t)bh * DD * TT;

    const u16* qp = q + base + (size_t)(t0 + (w << 4) + col) * EE + (quad << 3);
    const bf16x8 qf0 = *(const bf16x8*)qp;
    const bf16x8 qf1 = *(const bf16x8*)(qp + 32);

    float m_i[4], l_i[4];
    f32x4 acc_o[4];
#pragma unroll
    for (int r = 0; r < 4; r++) { m_i[r] = -1e30f; l_i[r] = 0.f; }
#pragma unroll
    for (int nt = 0; nt < 4; nt++) acc_o[nt] = (f32x4){0.f, 0.f, 0.f, 0.f};

    const int c_lo = 1 + ((t0 < WQ) ? ((WQ - t0) >> 6) : 0);
    const int c_hi = min(9, 1 + ((TT + WQ - 64 - t0) >> 6));

    const int srow  = tid >> 2;
    const int spart = (tid & 3) << 4;

    auto process = [&](int kpos0, int jbase) {
        {
            const u16* ks = k + base + (size_t)(kpos0 + srow) * EE + spart;
            const u16* vs = vt + vtbase + (size_t)srow * TT + kpos0 + spart;
            const uint4 k0v = *(const uint4*)ks;
            const uint4 k1v = *(const uint4*)(ks + 8);
            const uint4 v0v = *(const uint4*)vs;
            const uint4 v1v = *(const uint4*)(vs + 8);
            *(uint4*)&Ks[srow][spart]     = k0v;
            *(uint4*)&Ks[srow][spart + 8] = k1v;
            *(uint4*)&Vs[srow][spart]     = v0v;
            *(uint4*)&Vs[srow][spart + 8] = v1v;
        }
        __syncthreads();

        f32x4 acc_s[4];
#pragma unroll
        for (int nt = 0; nt < 4; nt++) {
            const bf16x8 kf0 = *(const bf16x8*)&Ks[(nt << 4) + col][quad << 3];
            const bf16x8 kf1 = *(const bf16x8*)&Ks[(nt << 4) + col][32 + (quad << 3)];
            f32x4 s = (f32x4){0.f, 0.f, 0.f, 0.f};
            s = __builtin_amdgcn_mfma_f32_16x16x32_bf16(qf0, kf0, s, 0, 0, 0);
            s = __builtin_amdgcn_mfma_f32_16x16x32_bf16(qf1, kf1, s, 0, 0, 0);
            acc_s[nt] = s;
        }

        if (jbase >= 0) {
#pragma unroll
            for (int nt = 0; nt < 4; nt++) {
#pragma unroll
                for (int r = 0; r < 4; r++) {
                    const int jp   = jbase + (nt << 4) + col;
                    const int qrow = (w << 4) + (quad << 2) + r;
                    const bool ok  = (jp >= qrow) && (jp <= qrow + 2 * WQ);
                    if (!ok) acc_s[nt][r] = -1e30f;
                }
            }
        }

        float p_sum[4];
#pragma unroll
        for (int r = 0; r < 4; r++) {
            float mx = fmaxf(fmaxf(acc_s[0][r], acc_s[1][r]), fmaxf(acc_s[2][r], acc_s[3][r]));
#pragma unroll
            for (int off = 1; off < 16; off <<= 1) mx = fmaxf(mx, __shfl_xor(mx, off));
            const float m_new = fmaxf(m_i[r], mx);
            const float alpha = __expf(m_i[r] - m_new);
            m_i[r] = m_new;
            l_i[r] *= alpha;
#pragma unroll
            for (int nt = 0; nt < 4; nt++) acc_o[nt][r] *= alpha;
            float ps = 0.f;
#pragma unroll
            for (int nt = 0; nt < 4; nt++) {
                const float e = __expf(acc_s[nt][r] - m_new);
                acc_s[nt][r] = e;
                ps += e;
            }
            p_sum[r] = ps;
        }
#pragma unroll
        for (int r = 0; r < 4; r++) {
            float ps = p_sum[r];
#pragma unroll
            for (int off = 1; off < 16; off <<= 1) ps += __shfl_xor(ps, off);
            l_i[r] += ps;
        }

#pragma unroll
        for (int nt = 0; nt < 4; nt++)
#pragma unroll
            for (int r = 0; r < 4; r++)
                Ps[w][(quad << 2) + r][(nt << 4) + col] = f2bf(acc_s[nt][r]);

        const bf16x8 pf0 = *(const bf16x8*)&Ps[w][col][quad << 3];
        const bf16x8 pf1 = *(const bf16x8*)&Ps[w][col][32 + (quad << 3)];

#pragma unroll
        for (int nt = 0; nt < 4; nt++) {
            const bf16x8 vf0 = *(const bf16x8*)&Vs[(nt << 4) + col][quad << 3];
            const bf16x8 vf1 = *(const bf16x8*)&Vs[(nt << 4) + col][32 + (quad << 3)];
            acc_o[nt] = __builtin_amdgcn_mfma_f32_16x16x32_bf16(pf0, vf0, acc_o[nt], 0, 0, 0);
            acc_o[nt] = __builtin_amdgcn_mfma_f32_16x16x32_bf16(pf1, vf1, acc_o[nt], 0, 0, 0);
        }
        __syncthreads();
    };

    process(0, -1);
#pragma unroll 1
    for (int c = c_lo; c <= c_hi; c++) {
        const int kpos0 = t0 - WQ + ((c - 1) << 6);
        const bool edge = (c == 1) || (c == 9);
        process(kpos0, edge ? ((c - 1) << 6) : -1);
    }

    float inv[4];
#pragma unroll
    for (int r = 0; r < 4; r++) inv[r] = 1.f / l_i[r];
#pragma unroll
    for (int nt = 0; nt < 4; nt++) {
#pragma unroll
        for (int r = 0; r < 4; r++) {
            const int t = t0 + (w << 4) + (quad << 2) + r;
            attnb[base + (size_t)t * EE + (nt << 4) + col] = f2bf(acc_o[nt][r] * inv[r]);
        }
    }
}

// ---------- global-token attention, MFMA flash + split-K ---------- (unchanged, passing)
__global__ __launch_bounds__(256) void global_attn_flash_kernel(
    const u16* __restrict__ qg, const u16* __restrict__ kg, const u16* __restrict__ vg,
    float* __restrict__ Op, float* __restrict__ Ml, float* __restrict__ Ll)
{
    const int tid  = threadIdx.x;
    const int lane = tid & 63;
    const int w    = tid >> 6;
    const int col  = lane & 15;
    const int quad = lane >> 4;

    const int s  = blockIdx.x & (NSPLIT - 1);
    const int h  = (blockIdx.x >> 3) & (HH - 1);
    const int b  = blockIdx.x >> 7;
    const int k0pos = s * (TT / NSPLIT);

    __shared__ __align__(16) u16 Qs[64][72];
    __shared__ __align__(16) u16 Ks[64][72];
    __shared__ __align__(16) u16 Vs[64][70];
    __shared__ __align__(16) u16 Ps[4][16][72];

    const size_t base = (size_t)b * TT * EE + (size_t)h * DD;

    {
        const int qr   = tid >> 2;
        const int part = (tid & 3) << 4;
        const uint4* src = (const uint4*)(qg + (size_t)(b * GG + qr) * EE + (size_t)h * DD + part);
        *(uint4*)&Qs[qr][part]     = src[0];
        *(uint4*)&Qs[qr][part + 8] = src[1];
    }

    float m_i[4], l_i[4];
    f32x4 acc_o[4];
#pragma unroll
    for (int r = 0; r < 4; r++) { m_i[r] = -1e30f; l_i[r] = 0.f; }
#pragma unroll
    for (int nt = 0; nt < 4; nt++) acc_o[nt] = (f32x4){0.f, 0.f, 0.f, 0.f};

#pragma unroll 1
    for (int cc = 0; cc < TT / NSPLIT / 64; cc++) {
        {
            const int kk   = tid >> 2;
            const int part = (tid & 3) << 4;
            const int pos  = k0pos + (cc << 6) + kk;
            const uint4* ks = (const uint4*)(kg + base + (size_t)pos * EE + part);
            const uint4* vs = (const uint4*)(vg + base + (size_t)pos * EE + part);
            const uint4 k0v = ks[0], k1v = ks[1];
            const uint4 v0v = vs[0], v1v = vs[1];
            *(uint4*)&Ks[kk][part]     = k0v;
            *(uint4*)&Ks[kk][part + 8] = k1v;
            unsigned int* vd = (unsigned int*)&Vs[kk][part];
            vd[0] = v0v.x; vd[1] = v0v.y; vd[2] = v0v.z; vd[3] = v0v.w;
            vd[4] = v1v.x; vd[5] = v1v.y; vd[6] = v1v.z; vd[7] = v1v.w;
        }
        __syncthreads();

        bf16x8 qf0 = *(const bf16x8*)&Qs[(w << 4) + col][quad << 3];
        bf16x8 qf1 = *(const bf16x8*)&Qs[(w << 4) + col][32 + (quad << 3)];
        f32x4 acc_s[4];
#pragma unroll
        for (int nt = 0; nt < 4; nt++) {
            bf16x8 kf0 = *(const bf16x8*)&Ks[(nt << 4) + col][quad << 3];
            bf16x8 kf1 = *(const bf16x8*)&Ks[(nt << 4) + col][32 + (quad << 3)];
            f32x4 sv = (f32x4){0.f, 0.f, 0.f, 0.f};
            sv = __builtin_amdgcn_mfma_f32_16x16x32_bf16(qf0, kf0, sv, 0, 0, 0);
            sv = __builtin_amdgcn_mfma_f32_16x16x32_bf16(qf1, kf1, sv, 0, 0, 0);
            acc_s[nt] = sv;
        }

        float m_c[4], p_sum[4];
#pragma unroll
        for (int r = 0; r < 4; r++) {
            float mx = fmaxf(fmaxf(acc_s[0][r], acc_s[1][r]), fmaxf(acc_s[2][r], acc_s[3][r]));
#pragma unroll
            for (int off = 1; off < 16; off <<= 1) mx = fmaxf(mx, __shfl_xor(mx, off));
            m_c[r] = mx;
        }
#pragma unroll
        for (int r = 0; r < 4; r++) {
            const float m_new = fmaxf(m_i[r], m_c[r]);
            const float alpha = __expf(m_i[r] - m_new);
            m_i[r] = m_new;
            l_i[r] *= alpha;
#pragma unroll
            for (int nt = 0; nt < 4; nt++) acc_o[nt][r] *= alpha;
            float ps = 0.f;
#pragma unroll
            for (int nt = 0; nt < 4; nt++) {
                const float e = __expf(acc_s[nt][r] - m_new);
                acc_s[nt][r] = e;
                ps += e;
            }
            p_sum[r] = ps;
        }
#pragma unroll
        for (int r = 0; r < 4; r++) {
            float ps = p_sum[r];
#pragma unroll
            for (int off = 1; off < 16; off <<= 1) ps += __shfl_xor(ps, off);
            l_i[r] += ps;
        }

#pragma unroll
        for (int nt = 0; nt < 4; nt++)
#pragma unroll
            for (int r = 0; r < 4; r++)
                Ps[w][(quad << 2) + r][(nt << 4) + col] = f2bf(acc_s[nt][r]);

        bf16x8 pf0 = *(const bf16x8*)&Ps[w][col][quad << 3];
        bf16x8 pf1 = *(const bf16x8*)&Ps[w][col][32 + (quad << 3)];
#pragma unroll
        for (int nt = 0; nt < 4; nt++) {
            union { bf16x8 v; u16 e[8]; } vf0, vf1;
#pragma unroll
            for (int j = 0; j < 8; j++) {
                vf0.e[j] = Vs[(quad << 3) + j][(nt << 4) + col];
                vf1.e[j] = Vs[32 + (quad << 3) + j][(nt << 4) + col];
            }
            acc_o[nt] = __builtin_amdgcn_mfma_f32_16x16x32_bf16(pf0, vf0.v, acc_o[nt], 0, 0, 0);
            acc_o[nt] = __builtin_amdgcn_mfma_f32_16x16x32_bf16(pf1, vf1.v, acc_o[nt], 0, 0, 0);
        }
        __syncthreads();
    }

    const size_t obase = (size_t)blockIdx.x * GG * DD;
#pragma unroll
    for (int nt = 0; nt < 4; nt++) {
#pragma unroll
        for (int r = 0; r < 4; r++) {
            const int row = (w << 4) + (quad << 2) + r;
            Op[obase + (size_t)row * DD + (nt << 4) + col] = acc_o[nt][r];
        }
    }
    if (col == 0) {
#pragma unroll
        for (int r = 0; r < 4; r++) {
            const int row = (w << 4) + (quad << 2) + r;
            Ml[blockIdx.x * GG + row] = m_i[r];
            Ll[blockIdx.x * GG + row] = l_i[r];
        }
    }
}

// ---------- combine split-K partials ---------- (unchanged, passing)
__global__ __launch_bounds__(256) void global_combine_kernel(
    const float* __restrict__ Op, const float* __restrict__ Ml, const float* __restrict__ Ll,
    u16* __restrict__ attnb)
{
    const int bh  = blockIdx.x;
    const int b   = bh >> 4;
    const int h   = bh & (HH - 1);
    const int row = threadIdx.x >> 2;
    const int d0  = (threadIdx.x & 3) << 4;

    float mv[NSPLIT];
    float m = -1e30f;
#pragma unroll
    for (int s = 0; s < NSPLIT; s++) {
        mv[s] = Ml[(bh * NSPLIT + s) * GG + row];
        m = fmaxf(m, mv[s]);
    }
    float l = 0.f;
    float sc[NSPLIT];
#pragma unroll
    for (int s = 0; s < NSPLIT; s++) {
        sc[s] = __expf(mv[s] - m);
        l += Ll[(bh * NSPLIT + s) * GG + row] * sc[s];
    }
    float o[16];
#pragma unroll
    for (int j = 0; j < 16; j++) o[j] = 0.f;
#pragma unroll
    for (int s = 0; s < NSPLIT; s++) {
        const float* src = Op + ((size_t)(bh * NSPLIT + s) * GG + row) * DD + d0;
        const float f = sc[s];
#pragma unroll
        for (int j = 0; j < 16; j += 4) {
            const float4 v4 = *(const float4*)(src + j);
            o[j + 0] = fmaf(v4.x, f, o[j + 0]);
            o[j + 1] = fmaf(v4.y, f, o[j + 1]);
            o[j + 2] = fmaf(v4.z, f, o[j + 2]);
            o[j + 3] = fmaf(v4.w, f, o[j + 3]);
        }
    }
    const float inv = 1.f / l;
    u16* dst = attnb + ((size_t)b * TT + row) * EE + (size_t)h * DD + d0;
#pragma unroll
    for (int j = 0; j < 16; j++) dst[j] = f2bf(o[j] * inv);
}

extern "C" void kernel_launch(void* const* d_in, const int* in_sizes, int n_in,
                              void* d_out, int out_size, void* d_ws, size_t ws_size,
                              hipStream_t stream)
{
    (void)in_sizes; (void)n_in; (void)out_size; (void)ws_size;
    const float* query = (const float*)d_in[0];
    const float* Wq  = (const float*)d_in[2];  const float* bq  = (const float*)d_in[3];
    const float* Wk  = (const float*)d_in[4];  const float* bk  = (const float*)d_in[5];
    const float* Wv  = (const float*)d_in[6];  const float* bv  = (const float*)d_in[7];
    const float* Wqg = (const float*)d_in[8];  const float* bqg = (const float*)d_in[9];
    const float* Wkg = (const float*)d_in[10]; const float* bkg = (const float*)d_in[11];
    const float* Wvg = (const float*)d_in[12]; const float* bvg = (const float*)d_in[13];
    const float* Wo  = (const float*)d_in[14]; const float* bo  = (const float*)d_in[15];

    const size_t nfull = (size_t)BBATCH * TT * EE;      // 8.39M elems
    const size_t wsz   = (size_t)1 << 20;               // one weight, elems
    u16* xb    = (u16*)d_ws;                            // bf16 x [B,T,E]; later reused as attnb
    u16* wb    = xb + nfull;                            // 7 converted weights
    u16* slotA = wb + 7 * wsz;                          // kg, then q
    u16* slotB = slotA + nfull;                         // vg, then k
    u16* slotC = slotB + nfull;                         // vt [B,H,D,T]
    u16* qg    = slotC + nfull;                         // [B*G, E]
    float* Op  = (float*)(qg + (size_t)BBATCH * GG * EE);
    float* Ml  = Op + (size_t)BBATCH * HH * NSPLIT * GG * DD;
    float* Ll  = Ml + (size_t)BBATCH * HH * NSPLIT * GG;
    u16* attnb = xb;                                    // alias: xb dead after last GEMM that reads it
    // peak ws ≈ 86 MB

    WPtrs wp;   // order: fuse3 (Wq,Wk,Wv) | fuse2 (Wkg,Wvg) | Wqg | Wo
    wp.p[0] = Wq; wp.p[1] = Wk; wp.p[2] = Wv;
    wp.p[3] = Wkg; wp.p[4] = Wvg; wp.p[5] = Wqg; wp.p[6] = Wo;

    const dim3 blk(256);
    const dim3 gF2(16, 64);     // N=2048
    const dim3 gF3(24, 64);     // N=3072
    const dim3 gFull(8, 64);    // N=1024
    const dim3 gQg(8, 1);
    const float sc = 0.125f;    // D^-0.5

    conv_kernel<<<7680, blk, 0, stream>>>(wp, query, wb, xb);

    // qg projection (reads xb)
    gemm_kernel<0, 1, 0><<<gQg, blk, 0, stream>>>(xb, wb + 5 * wsz, bqg, qg, sc);

    // fused kg|vg projection, then flash (frees slotA/slotB)
    FusedArgs fa2;
    fa2.out[0] = slotA; fa2.out[1] = slotB; fa2.out[2] = nullptr;
    fa2.bias[0] = bkg;  fa2.bias[1] = bvg;  fa2.bias[2] = nullptr;
    fa2.scale[0] = 1.f; fa2.scale[1] = 1.f; fa2.scale[2] = 1.f;
    fa2.vseg = -1;
    gemm_fused_kernel<2><<<gF2, blk, 0, stream>>>(xb, wb + 3 * wsz, fa2);
    global_attn_flash_kernel<<<BBATCH * HH * NSPLIT, blk, 0, stream>>>(qg, slotA, slotB, Op, Ml, Ll);

    // fused q|k|vt projection
    FusedArgs fa3;
    fa3.out[0] = slotA; fa3.out[1] = slotB; fa3.out[2] = slotC;
    fa3.bias[0] = bq;   fa3.bias[1] = bk;   fa3.bias[2] = bv;
    fa3.scale[0] = sc;  fa3.scale[1] = 1.f; fa3.scale[2] = 1.f;
    fa3.vseg = 2;
    gemm_fused_kernel<3><<<gF3, blk, 0, stream>>>(xb, wb, fa3);

    band_attn_kernel<<<BBATCH * HH * (TT / 64), blk, 0, stream>>>(slotA, slotB, slotC, attnb);
    global_combine_kernel<<<BBATCH * HH, blk, 0, stream>>>(Op, Ml, Ll, attnb);

    gemm_kernel<1, 0, 1><<<gFull, blk, 0, stream>>>(attnb, wb + 6 * wsz, bo, (void*)d_out, 1.f);
}